// Round 1
// baseline (65.818 us; speedup 1.0000x reference)
//
#include <hip/hip_runtime.h>

// SelfAttentionHead: B=16, T=1024, C=768, H=64, fp32 in/out, causal softmax.
// Kernel 1 (proj): Q/K/V = x @ W{q,k,v}, computed in f16 MFMA, stored f16 in ws.
// Kernel 2 (attn): flash-style causal attention, 64-row q-tiles, online softmax.

typedef _Float16 half8 __attribute__((ext_vector_type(8)));
typedef _Float16 half4 __attribute__((ext_vector_type(4)));
typedef float float4v __attribute__((ext_vector_type(4)));

#define NB   16
#define NT   1024
#define NC   768
#define NH   64

// ---------------------------------------------------------------------------
// Projection: x [16384][768] fp32  @  W [768][64] fp32 (x3) -> f16 out [16384][64] x3
// Grid: 256 blocks (64 rows each), 512 threads = 8 waves.
// Wave (wm, wn): wm in {0,1} picks 32-row half, wn in {0..3} picks 48 of the
// 192 concatenated output columns (Q|K|V). MFMA 16x16x32 f16.
// ---------------------------------------------------------------------------
__global__ __launch_bounds__(512) void proj_kernel(
    const float* __restrict__ x, const float* __restrict__ Wk,
    const float* __restrict__ Wq, const float* __restrict__ Wv,
    _Float16* __restrict__ Qb, _Float16* __restrict__ Kb, _Float16* __restrict__ Vb)
{
    __shared__ _Float16 xl[64][40];   // 64 rows x 32 k, +8 pad (80B row stride)

    const int t   = threadIdx.x;
    const int wid = t >> 6, lane = t & 63;
    const int l15 = lane & 15, lhi = lane >> 4;
    const int wn  = wid & 3,  wm  = wid >> 2;
    const int m0  = blockIdx.x * 64;
    const int srow = t >> 3, sk = (t & 7) * 4;   // staging: 4 floats/thread

    const float* Ws[3] = { Wq, Wk, Wv };
    const int gcol0 = wn * 48;

    float4v acc[2][3];
#pragma unroll
    for (int i = 0; i < 2; ++i)
#pragma unroll
        for (int j = 0; j < 3; ++j)
            acc[i][j] = (float4v){0.f, 0.f, 0.f, 0.f};

    for (int kc = 0; kc < 24; ++kc) {
        // global loads first (no LDS dependence): x chunk + W fragments
        float4v f0 = *(const float4v*)(x + (size_t)(m0 + srow) * NC + kc * 32 + sk);

        half8 bfr[3];
#pragma unroll
        for (int nf = 0; nf < 3; ++nf) {
            const int gc = gcol0 + nf * 16;
            const float* W = Ws[gc >> 6];
            const float* wp = W + (size_t)(kc * 32 + lhi * 8) * NH + (gc & 63) + l15;
            half8 bb;
#pragma unroll
            for (int j = 0; j < 8; ++j) bb[j] = (_Float16)wp[j * NH];
            bfr[nf] = bb;
        }

        __syncthreads();   // previous iteration's LDS reads done
        half4 xs;
        xs[0] = (_Float16)f0[0]; xs[1] = (_Float16)f0[1];
        xs[2] = (_Float16)f0[2]; xs[3] = (_Float16)f0[3];
        *(half4*)&xl[srow][sk] = xs;
        __syncthreads();   // tile ready

        half8 af[2];
#pragma unroll
        for (int i = 0; i < 2; ++i)
            af[i] = *(const half8*)&xl[(wm * 2 + i) * 16 + l15][lhi * 8];

#pragma unroll
        for (int i = 0; i < 2; ++i)
#pragma unroll
            for (int nf = 0; nf < 3; ++nf)
                acc[i][nf] = __builtin_amdgcn_mfma_f32_16x16x32_f16(
                    af[i], bfr[nf], acc[i][nf], 0, 0, 0);
    }

    _Float16* Ds[3] = { Qb, Kb, Vb };
#pragma unroll
    for (int nf = 0; nf < 3; ++nf) {
        const int gc = gcol0 + nf * 16;
        _Float16* D = Ds[gc >> 6];
        const int col = (gc & 63) + l15;
#pragma unroll
        for (int i = 0; i < 2; ++i)
#pragma unroll
            for (int r = 0; r < 4; ++r) {
                const int row = m0 + (wm * 2 + i) * 16 + lhi * 4 + r;
                D[(size_t)row * NH + col] = (_Float16)acc[i][nf][r];
            }
    }
}

// ---------------------------------------------------------------------------
// Flash attention, causal. Grid: (16 q-tiles, 16 batches), 256 threads = 4 waves.
// Wave w owns q-rows [w*16, w*16+16). Online softmax state per lane: 4 rows
// (D-layout rows lhi*4+r), stats replicated across the 16-lane column group.
// ---------------------------------------------------------------------------
__global__ __launch_bounds__(256) void attn_kernel(
    const _Float16* __restrict__ Qb, const _Float16* __restrict__ Kb,
    const _Float16* __restrict__ Vb, float* __restrict__ out)
{
    __shared__ _Float16 Ql[64][72];
    __shared__ _Float16 Kl[64][72];
    __shared__ _Float16 Vt[64][72];      // transposed: Vt[d][key]
    __shared__ _Float16 Pl[4][16][72];   // per-wave P buffer

    const int t = threadIdx.x, wid = t >> 6, lane = t & 63;
    const int l15 = lane & 15, lhi = lane >> 4;
    const int qi = blockIdx.x, b = blockIdx.y;
    const int qbase = qi * 64;
    const int srow = t >> 2, sc0 = (t & 3) * 16;

    {   // stage Q tile once
        const _Float16* src = Qb + ((size_t)(b * NT + qbase + srow)) * NH + sc0;
        *(half8*)&Ql[srow][sc0]     = *(const half8*)src;
        *(half8*)&Ql[srow][sc0 + 8] = *(const half8*)(src + 8);
    }
    __syncthreads();
    half8 aq[2];
    aq[0] = *(const half8*)&Ql[wid * 16 + l15][lhi * 8];
    aq[1] = *(const half8*)&Ql[wid * 16 + l15][32 + lhi * 8];

    float4v o[4];
#pragma unroll
    for (int nf = 0; nf < 4; ++nf) o[nf] = (float4v){0.f, 0.f, 0.f, 0.f};
    float mrow[4], lrow[4];
#pragma unroll
    for (int r = 0; r < 4; ++r) { mrow[r] = -1e30f; lrow[r] = 0.f; }

    for (int jt = 0; jt <= qi; ++jt) {
        // issue staging loads early
        const _Float16* ksrc = Kb + ((size_t)(b * NT + jt * 64 + srow)) * NH + sc0;
        const _Float16* vsrc = Vb + ((size_t)(b * NT + jt * 64 + srow)) * NH + sc0;
        half8 k0 = *(const half8*)ksrc;
        half8 k1 = *(const half8*)(ksrc + 8);
        half8 v0 = *(const half8*)vsrc;
        half8 v1 = *(const half8*)(vsrc + 8);
        __syncthreads();   // previous tile's K/V reads done
        *(half8*)&Kl[srow][sc0]     = k0;
        *(half8*)&Kl[srow][sc0 + 8] = k1;
#pragma unroll
        for (int jj = 0; jj < 8; ++jj) Vt[sc0 + jj][srow] = v0[jj];
#pragma unroll
        for (int jj = 0; jj < 8; ++jj) Vt[sc0 + 8 + jj][srow] = v1[jj];
        __syncthreads();

        // S = Q K^T  (K rows are k-contiguous => direct B-frag reads)
        float4v s[4];
#pragma unroll
        for (int nf = 0; nf < 4; ++nf) {
            half8 bk0 = *(const half8*)&Kl[nf * 16 + l15][lhi * 8];
            half8 bk1 = *(const half8*)&Kl[nf * 16 + l15][32 + lhi * 8];
            float4v sv = (float4v){0.f, 0.f, 0.f, 0.f};
            sv = __builtin_amdgcn_mfma_f32_16x16x32_f16(aq[0], bk0, sv, 0, 0, 0);
            sv = __builtin_amdgcn_mfma_f32_16x16x32_f16(aq[1], bk1, sv, 0, 0, 0);
            s[nf] = sv;
        }

        // scale + causal mask + row max
        const bool diag = (jt == qi);
        float pm[4] = {-1e30f, -1e30f, -1e30f, -1e30f};
#pragma unroll
        for (int nf = 0; nf < 4; ++nf)
#pragma unroll
            for (int r = 0; r < 4; ++r) {
                float v = s[nf][r] * 0.125f;   // 1/sqrt(64)
                if (diag) {
                    const int key = nf * 16 + l15;
                    const int qr  = wid * 16 + lhi * 4 + r;
                    if (key > qr) v = -1e30f;
                }
                s[nf][r] = v;
                pm[r] = fmaxf(pm[r], v);
            }
#pragma unroll
        for (int mask = 1; mask < 16; mask <<= 1)
#pragma unroll
            for (int r = 0; r < 4; ++r)
                pm[r] = fmaxf(pm[r], __shfl_xor(pm[r], mask));

        float mnew[4], esc[4], ssum[4];
#pragma unroll
        for (int r = 0; r < 4; ++r) {
            mnew[r] = fmaxf(mrow[r], pm[r]);
            esc[r]  = __expf(mrow[r] - mnew[r]);
            ssum[r] = 0.f;
        }
#pragma unroll
        for (int nf = 0; nf < 4; ++nf)
#pragma unroll
            for (int r = 0; r < 4; ++r) {
                const float p = __expf(s[nf][r] - mnew[r]);
                ssum[r] += p;
                Pl[wid][lhi * 4 + r][nf * 16 + l15] = (_Float16)p;
            }
#pragma unroll
        for (int mask = 1; mask < 16; mask <<= 1)
#pragma unroll
            for (int r = 0; r < 4; ++r)
                ssum[r] += __shfl_xor(ssum[r], mask);
#pragma unroll
        for (int r = 0; r < 4; ++r) {
            lrow[r] = lrow[r] * esc[r] + ssum[r];
            mrow[r] = mnew[r];
        }
#pragma unroll
        for (int nf = 0; nf < 4; ++nf)
#pragma unroll
            for (int r = 0; r < 4; ++r)
                o[nf][r] *= esc[r];

        // O += P V   (P via per-wave LDS round-trip; within-wave, no barrier)
#pragma unroll
        for (int ks = 0; ks < 2; ++ks) {
            half8 pa = *(const half8*)&Pl[wid][l15][ks * 32 + lhi * 8];
#pragma unroll
            for (int nf = 0; nf < 4; ++nf) {
                half8 bv = *(const half8*)&Vt[nf * 16 + l15][ks * 32 + lhi * 8];
                o[nf] = __builtin_amdgcn_mfma_f32_16x16x32_f16(pa, bv, o[nf], 0, 0, 0);
            }
        }
    }

    // epilogue: normalize and store fp32
#pragma unroll
    for (int nf = 0; nf < 4; ++nf)
#pragma unroll
        for (int r = 0; r < 4; ++r) {
            const int row = qbase + wid * 16 + lhi * 4 + r;
            out[((size_t)(b * NT + row)) * NH + nf * 16 + l15] = o[nf][r] / lrow[r];
        }
}

extern "C" void kernel_launch(void* const* d_in, const int* in_sizes, int n_in,
                              void* d_out, int out_size, void* d_ws, size_t ws_size,
                              hipStream_t stream) {
    const float* x  = (const float*)d_in[0];
    const float* Wk = (const float*)d_in[1];
    const float* Wq = (const float*)d_in[2];
    const float* Wv = (const float*)d_in[3];

    _Float16* Qb = (_Float16*)d_ws;                       // 2 MB
    _Float16* Kb = Qb + (size_t)NB * NT * NH;             // 2 MB
    _Float16* Vb = Kb + (size_t)NB * NT * NH;             // 2 MB

    proj_kernel<<<dim3(256), dim3(512), 0, stream>>>(x, Wk, Wq, Wv, Qb, Kb, Vb);
    attn_kernel<<<dim3(16, 16), dim3(256), 0, stream>>>(Qb, Kb, Vb, (float*)d_out);
}